// Round 3
// baseline (61030.511 us; speedup 1.0000x reference)
//
#include <hip/hip_runtime.h>
#include <stdint.h>

#define N_ELEM 262144
#define NBINS 16384 /* fine linear bins over [-8,8]; lambda~16, center ~102 */
#define TILE 32768
#define NBLK (N_ELEM / TILE) /* 8 */

__device__ __forceinline__ unsigned key_of(float x) {
    unsigned u = __float_as_uint(x);
    return u ^ ((u & 0x80000000u) ? 0xFFFFFFFFu : 0x80000000u);
}

// Monotone (non-decreasing) float -> bin. floor((x+8)*1024): the add rounds
// monotonically, *1024 is exact, floor is monotone. Clamping only affects
// load balance, never correctness (in-bin compare uses exact keys).
__device__ __forceinline__ int bin_of(float x) {
    int f = (int)floorf((x + 8.0f) * 1024.0f);
    f = f < 0 ? 0 : (f > NBINS - 1 ? NBINS - 1 : f);
    return f;
}

// --- Kernel A: per-(row,block) histogram of 16384 bins ---------------------
__global__ __launch_bounds__(512) void hist_kernel(
    const float* __restrict__ x, int r0, unsigned* __restrict__ blockHist) {
    __shared__ unsigned h[NBINS];
    const int crow = blockIdx.y, blk = blockIdx.x;
    for (int i = threadIdx.x; i < NBINS; i += 512) h[i] = 0;
    __syncthreads();
    const float4* p =
        (const float4*)(x + (size_t)(r0 + crow) * N_ELEM + (size_t)blk * TILE);
    for (int i = threadIdx.x; i < TILE / 4; i += 512) {
        float4 v = p[i];
        atomicAdd(&h[bin_of(v.x)], 1u);
        atomicAdd(&h[bin_of(v.y)], 1u);
        atomicAdd(&h[bin_of(v.z)], 1u);
        atomicAdd(&h[bin_of(v.w)], 1u);
    }
    __syncthreads();
    unsigned* out = blockHist + ((size_t)crow * NBLK + blk) * NBINS;
    for (int i = threadIdx.x; i < NBINS; i += 512) out[i] = h[i];
}

// --- Kernel B: per-row scan over [blk][bin] -> per-block scatter starts ----
__global__ void scan_kernel(unsigned* __restrict__ blockHist) {
    __shared__ unsigned ssum[256];
    const int crow = blockIdx.x;
    unsigned* bh = blockHist + (size_t)crow * NBLK * NBINS;
    const int t = threadIdx.x;
    const int K = NBINS / 256; // 64 bins per thread, blocked
    unsigned tsum = 0;
    for (int k = 0; k < K; k++) {
        int b = t * K + k;
        for (int blk = 0; blk < NBLK; blk++) tsum += bh[(size_t)blk * NBINS + b];
    }
    ssum[t] = tsum;
    __syncthreads();
    for (int off = 1; off < 256; off <<= 1) {
        unsigned v = (t >= off) ? ssum[t - off] : 0u;
        __syncthreads();
        ssum[t] += v;
        __syncthreads();
    }
    unsigned running = ssum[t] - tsum; // exclusive thread base
    for (int k = 0; k < K; k++) {
        int b = t * K + k;
        unsigned pre = running;
        for (int blk = 0; blk < NBLK; blk++) {
            size_t o = (size_t)blk * NBINS + b;
            unsigned c = bh[o];
            bh[o] = pre;
            pre += c;
        }
        running = pre;
    }
}

// --- Kernel C: scatter (key, origidx) records grouped by bin ---------------
__global__ __launch_bounds__(512) void scatter_kernel(
    const float* __restrict__ x, int r0, const unsigned* __restrict__ blockHist,
    uint2* __restrict__ rec) {
    __shared__ unsigned cur[NBINS];
    const int crow = blockIdx.y, blk = blockIdx.x;
    const unsigned* bs = blockHist + ((size_t)crow * NBLK + blk) * NBINS;
    for (int i = threadIdx.x; i < NBINS; i += 512) cur[i] = bs[i];
    __syncthreads();
    const float4* p =
        (const float4*)(x + (size_t)(r0 + crow) * N_ELEM + (size_t)blk * TILE);
    uint2* rr = rec + (size_t)crow * N_ELEM;
    const int ib = blk * TILE;
    for (int i = threadIdx.x; i < TILE / 4; i += 512) {
        float4 v = p[i];
        int i0 = ib + i * 4;
        float vv[4] = {v.x, v.y, v.z, v.w};
#pragma unroll
        for (int k = 0; k < 4; k++) {
            unsigned pos = atomicAdd(&cur[bin_of(vv[k])], 1u);
            rr[pos] = make_uint2(key_of(vv[k]), (unsigned)(i0 + k));
        }
    }
}

// --- Kernel D: one THREAD per bin; serial O(cnt^2) over contiguous segment.
// No LDS, no barriers -> high occupancy. Adjacent lanes = adjacent bins, so
// per-wave load is locally uniform (Gaussian density varies smoothly).
__global__ __launch_bounds__(256) void rank_kernel(
    const uint2* __restrict__ rec, const unsigned* __restrict__ blockHist,
    unsigned* __restrict__ rankP, int side) {
    const int b = blockIdx.x * 256 + threadIdx.x;
    const int crow = blockIdx.y;
    const unsigned* pf = blockHist + (size_t)crow * NBLK * NBINS; // blk0 = row prefix
    unsigned base = pf[b];
    unsigned end = (b + 1 < NBINS) ? pf[b + 1] : (unsigned)N_ELEM;
    if (end <= base) return;
    const uint2* r = rec + (size_t)crow * N_ELEM;
    unsigned* rp = rankP + (size_t)(crow * 2 + side) * N_ELEM;
    for (unsigned i = base; i < end; i++) {
        uint2 ei = r[i];
        unsigned long long Ki = ((unsigned long long)ei.x << 32) | i;
        unsigned c = 0;
        for (unsigned j = base; j < end; j++) {
            uint2 ej = r[j];
            unsigned long long Kj = ((unsigned long long)ej.x << 32) | j;
            c += (Kj < Ki) ? 1u : 0u;
        }
        rp[ei.y] = base + c + 1u;
    }
}

// --- Kernel E: coalesced exact dot S[row] = sum(rp*rt) in u64 --------------
__global__ __launch_bounds__(256) void dot_kernel(
    const unsigned* __restrict__ rankP, unsigned long long* __restrict__ S,
    int r0) {
    const int crow = blockIdx.y;
    const uint4* rp4 = (const uint4*)(rankP + (size_t)(crow * 2 + 0) * N_ELEM);
    const uint4* rt4 = (const uint4*)(rankP + (size_t)(crow * 2 + 1) * N_ELEM);
    const int t = threadIdx.x;
    const int base4 = blockIdx.x * (8192 / 4);
    unsigned long long acc = 0;
#pragma unroll
    for (int k = 0; k < 8; k++) {
        uint4 a = rp4[base4 + k * 256 + t];
        uint4 b = rt4[base4 + k * 256 + t];
        acc += (unsigned long long)a.x * b.x + (unsigned long long)a.y * b.y +
               (unsigned long long)a.z * b.z + (unsigned long long)a.w * b.w;
    }
    for (int off = 32; off > 0; off >>= 1) acc += __shfl_down(acc, off, 64);
    if ((t & 63) == 0) atomicAdd(&S[r0 + crow], acc);
}

// --- Kernel F: closed-form Pearson of two exact permutations + loss --------
__global__ void finalize_kernel(const unsigned long long* __restrict__ S, int B,
                                float* __restrict__ out) {
    __shared__ double sh[128];
    const int t = threadIdx.x;
    const double Nd = (double)N_ELEM;
    const double m = (Nd + 1.0) * 0.5;
    const double q = Nd * (Nd * Nd - 1.0) / 12.0;
    double c = 0.0;
    if (t < B) {
        double num = (double)(long long)S[t] - Nd * m * m;
        c = num / sqrt(q * q + 1e-8);
    }
    sh[t] = c;
    __syncthreads();
    for (int off = 64; off > 0; off >>= 1) {
        if (t < off) sh[t] += sh[t + off];
        __syncthreads();
    }
    double mean = sh[0] / (double)B;
    __syncthreads();
    double d = (t < B) ? (c - mean) : 0.0;
    sh[t] = d * d;
    __syncthreads();
    for (int off = 64; off > 0; off >>= 1) {
        if (t < off) sh[t] += sh[t + off];
        __syncthreads();
    }
    if (t == 0) {
        double var = sh[0] / (double)B;
        double stdv = sqrt(var) + 1e-8;
        double icir = mean / stdv;
        out[0] = (float)(-icir + 0.1 * stdv);
    }
}

extern "C" void kernel_launch(void* const* d_in, const int* in_sizes, int n_in,
                              void* d_out, int out_size, void* d_ws,
                              size_t ws_size, hipStream_t stream) {
    const float* pred = (const float*)d_in[0];
    const float* tru = (const float*)d_in[1];
    const int B = in_sizes[0] / N_ELEM; // 90

    char* ws = (char*)d_ws;
    unsigned long long* S = (unsigned long long*)ws;
    const size_t off0 = 4096;
    // per chunked row: blockHist 512KB + rec 2MB + rankP (both sides) 2MB
    const size_t perRow = (size_t)NBLK * NBINS * 4 + (size_t)N_ELEM * 8 +
                          (size_t)N_ELEM * 4 * 2;
    int R = (int)((ws_size > off0 ? ws_size - off0 : 0) / perRow);
    if (R > B) R = B;
    if (R < 1) R = 1;

    unsigned* blockHist = (unsigned*)(ws + off0);
    uint2* rec = (uint2*)(ws + off0 + (size_t)R * NBLK * NBINS * 4);
    unsigned* rankP = (unsigned*)(ws + off0 + (size_t)R * NBLK * NBINS * 4 +
                                  (size_t)R * N_ELEM * 8);

    hipMemsetAsync(S, 0, (size_t)B * 8, stream);

    for (int r0 = 0; r0 < B; r0 += R) {
        int RR = (B - r0 < R) ? (B - r0) : R;
        for (int side = 0; side < 2; side++) {
            const float* x = side ? tru : pred;
            hist_kernel<<<dim3(NBLK, RR), 512, 0, stream>>>(x, r0, blockHist);
            scan_kernel<<<RR, 256, 0, stream>>>(blockHist);
            scatter_kernel<<<dim3(NBLK, RR), 512, 0, stream>>>(x, r0, blockHist,
                                                               rec);
            rank_kernel<<<dim3(NBINS / 256, RR), 256, 0, stream>>>(
                rec, blockHist, rankP, side);
        }
        dot_kernel<<<dim3(N_ELEM / 8192, RR), 256, 0, stream>>>(rankP, S, r0);
    }
    finalize_kernel<<<1, 128, 0, stream>>>(S, B, (float*)d_out);
}

// Round 4
// 2077.614 us; speedup vs baseline: 29.3753x; 29.3753x over previous
//
#include <hip/hip_runtime.h>
#include <stdint.h>

#define N_ELEM 262144
#define NBINS 16384 /* fine linear bins over [-8,8]; center bin ~102 elems */
#define TILE 32768
#define NBLK (N_ELEM / TILE) /* 8 */
#define BPB 16   /* bins per rank block: center segment ~1632 records */
#define CAP 2560 /* LDS record capacity; overflow -> global fallback */

__device__ __forceinline__ unsigned key_of(float x) {
    unsigned u = __float_as_uint(x);
    return u ^ ((u & 0x80000000u) ? 0xFFFFFFFFu : 0x80000000u);
}

// Monotone (non-decreasing) float -> bin. floor((x+8)*1024): the add rounds
// monotonically, *1024 is exact, floor is monotone. Clamping only affects
// load balance, never correctness (in-bin compare uses exact keys).
__device__ __forceinline__ int bin_of(float x) {
    int f = (int)floorf((x + 8.0f) * 1024.0f);
    f = f < 0 ? 0 : (f > NBINS - 1 ? NBINS - 1 : f);
    return f;
}

// --- Kernel A: per-(row,block) histogram of 16384 bins ---------------------
__global__ __launch_bounds__(512) void hist_kernel(
    const float* __restrict__ x, int r0, unsigned* __restrict__ blockHist) {
    __shared__ unsigned h[NBINS];
    const int crow = blockIdx.y, blk = blockIdx.x;
    for (int i = threadIdx.x; i < NBINS; i += 512) h[i] = 0;
    __syncthreads();
    const float4* p =
        (const float4*)(x + (size_t)(r0 + crow) * N_ELEM + (size_t)blk * TILE);
    for (int i = threadIdx.x; i < TILE / 4; i += 512) {
        float4 v = p[i];
        atomicAdd(&h[bin_of(v.x)], 1u);
        atomicAdd(&h[bin_of(v.y)], 1u);
        atomicAdd(&h[bin_of(v.z)], 1u);
        atomicAdd(&h[bin_of(v.w)], 1u);
    }
    __syncthreads();
    unsigned* out = blockHist + ((size_t)crow * NBLK + blk) * NBINS;
    for (int i = threadIdx.x; i < NBINS; i += 512) out[i] = h[i];
}

// --- Kernel B: per-row scan over [blk][bin] -> per-block scatter starts ----
// After this, blk-0 plane holds the row-level exclusive bin prefix.
__global__ void scan_kernel(unsigned* __restrict__ blockHist) {
    __shared__ unsigned ssum[256];
    const int crow = blockIdx.x;
    unsigned* bh = blockHist + (size_t)crow * NBLK * NBINS;
    const int t = threadIdx.x;
    const int K = NBINS / 256; // 64 bins per thread, blocked
    unsigned tsum = 0;
    for (int k = 0; k < K; k++) {
        int b = t * K + k;
        for (int blk = 0; blk < NBLK; blk++) tsum += bh[(size_t)blk * NBINS + b];
    }
    ssum[t] = tsum;
    __syncthreads();
    for (int off = 1; off < 256; off <<= 1) {
        unsigned v = (t >= off) ? ssum[t - off] : 0u;
        __syncthreads();
        ssum[t] += v;
        __syncthreads();
    }
    unsigned running = ssum[t] - tsum; // exclusive thread base
    for (int k = 0; k < K; k++) {
        int b = t * K + k;
        unsigned pre = running;
        for (int blk = 0; blk < NBLK; blk++) {
            size_t o = (size_t)blk * NBINS + b;
            unsigned c = bh[o];
            bh[o] = pre;
            pre += c;
        }
        running = pre;
    }
}

// --- Kernel C: scatter (key, bin<<18|idx) records grouped by bin -----------
// idx < 2^18 (N=262144), bin < 2^14 -> exactly 32 bits.
__global__ __launch_bounds__(512) void scatter_kernel(
    const float* __restrict__ x, int r0, const unsigned* __restrict__ blockHist,
    uint2* __restrict__ rec) {
    __shared__ unsigned cur[NBINS];
    const int crow = blockIdx.y, blk = blockIdx.x;
    const unsigned* bs = blockHist + ((size_t)crow * NBLK + blk) * NBINS;
    for (int i = threadIdx.x; i < NBINS; i += 512) cur[i] = bs[i];
    __syncthreads();
    const float4* p =
        (const float4*)(x + (size_t)(r0 + crow) * N_ELEM + (size_t)blk * TILE);
    uint2* rr = rec + (size_t)crow * N_ELEM;
    const int ib = blk * TILE;
    for (int i = threadIdx.x; i < TILE / 4; i += 512) {
        float4 v = p[i];
        int i0 = ib + i * 4;
        float vv[4] = {v.x, v.y, v.z, v.w};
#pragma unroll
        for (int k = 0; k < 4; k++) {
            unsigned b = (unsigned)bin_of(vv[k]);
            unsigned pos = atomicAdd(&cur[b], 1u);
            rr[pos] = make_uint2(key_of(vv[k]), (b << 18) | (unsigned)(i0 + k));
        }
    }
}

// --- Kernel D: rank. Block = 16 consecutive bins = one contiguous rec
// segment. Coalesced LDS stage, then per-thread in-bin counting. Threads
// stride by 1 -> a wave's 64 lanes sit in the same bin -> LDS broadcast
// reads, uniform inner-loop lengths.
__global__ __launch_bounds__(256) void rank_kernel(
    const uint2* __restrict__ rec, const unsigned* __restrict__ blockHist,
    unsigned* __restrict__ rankP, int side) {
    const int crow = blockIdx.y;
    const int b0 = blockIdx.x * BPB;
    const unsigned* pf = blockHist + (size_t)crow * NBLK * NBINS; // row prefix
    __shared__ unsigned pfL[BPB + 1];
    if (threadIdx.x <= BPB) {
        int b = b0 + threadIdx.x;
        pfL[threadIdx.x] = (b < NBINS) ? pf[b] : (unsigned)N_ELEM;
    }
    __syncthreads();
    const unsigned segBase = pfL[0];
    const unsigned segEnd = pfL[BPB];
    const int n = (int)(segEnd - segBase);
    if (n <= 0) return;
    const uint2* r = rec + (size_t)crow * N_ELEM;
    unsigned* rp = rankP + (size_t)(crow * 2 + side) * N_ELEM;

    if (n <= CAP) {
        __shared__ unsigned sk[CAP], sy[CAP];
        for (int j = threadIdx.x; j < n; j += 256) {
            uint2 e = r[segBase + j];
            sk[j] = e.x;
            sy[j] = e.y;
        }
        __syncthreads();
        for (int j = threadIdx.x; j < n; j += 256) {
            unsigned y = sy[j];
            unsigned bl = (y >> 18) - (unsigned)b0; // block-local bin
            unsigned lo = pfL[bl] - segBase;
            unsigned hi = pfL[bl + 1] - segBase;
            unsigned long long myK =
                ((unsigned long long)sk[j] << 32) | (unsigned)j;
            unsigned c = 0;
            for (unsigned k = lo; k < hi; k++) {
                unsigned long long K = ((unsigned long long)sk[k] << 32) | k;
                c += (K < myK) ? 1u : 0u;
            }
            rp[y & 0x3FFFFu] = segBase + lo + c + 1u;
        }
    } else { // safety fallback (never expected for N(0,1) inputs)
        for (int j = threadIdx.x; j < n; j += 256) {
            uint2 e = r[segBase + j];
            unsigned bin = e.y >> 18;
            unsigned lo = pf[bin];
            unsigned hi = (bin + 1 < NBINS) ? pf[bin + 1] : (unsigned)N_ELEM;
            unsigned long long myK =
                ((unsigned long long)e.x << 32) | (segBase + (unsigned)j);
            unsigned c = 0;
            for (unsigned k = lo; k < hi; k++) {
                uint2 ek = r[k];
                unsigned long long K = ((unsigned long long)ek.x << 32) | k;
                c += (K < myK) ? 1u : 0u;
            }
            rp[e.y & 0x3FFFFu] = lo + c + 1u;
        }
    }
}

// --- Kernel E: coalesced exact dot S[row] = sum(rp*rt) in u64 --------------
__global__ __launch_bounds__(256) void dot_kernel(
    const unsigned* __restrict__ rankP, unsigned long long* __restrict__ S,
    int r0) {
    const int crow = blockIdx.y;
    const uint4* rp4 = (const uint4*)(rankP + (size_t)(crow * 2 + 0) * N_ELEM);
    const uint4* rt4 = (const uint4*)(rankP + (size_t)(crow * 2 + 1) * N_ELEM);
    const int t = threadIdx.x;
    const int base4 = blockIdx.x * (8192 / 4);
    unsigned long long acc = 0;
#pragma unroll
    for (int k = 0; k < 8; k++) {
        uint4 a = rp4[base4 + k * 256 + t];
        uint4 b = rt4[base4 + k * 256 + t];
        acc += (unsigned long long)a.x * b.x + (unsigned long long)a.y * b.y +
               (unsigned long long)a.z * b.z + (unsigned long long)a.w * b.w;
    }
    for (int off = 32; off > 0; off >>= 1) acc += __shfl_down(acc, off, 64);
    if ((t & 63) == 0) atomicAdd(&S[r0 + crow], acc);
}

// --- Kernel F: closed-form Pearson of two exact permutations + loss --------
__global__ void finalize_kernel(const unsigned long long* __restrict__ S, int B,
                                float* __restrict__ out) {
    __shared__ double sh[128];
    const int t = threadIdx.x;
    const double Nd = (double)N_ELEM;
    const double m = (Nd + 1.0) * 0.5;
    const double q = Nd * (Nd * Nd - 1.0) / 12.0;
    double c = 0.0;
    if (t < B) {
        double num = (double)(long long)S[t] - Nd * m * m;
        c = num / sqrt(q * q + 1e-8);
    }
    sh[t] = c;
    __syncthreads();
    for (int off = 64; off > 0; off >>= 1) {
        if (t < off) sh[t] += sh[t + off];
        __syncthreads();
    }
    double mean = sh[0] / (double)B;
    __syncthreads();
    double d = (t < B) ? (c - mean) : 0.0;
    sh[t] = d * d;
    __syncthreads();
    for (int off = 64; off > 0; off >>= 1) {
        if (t < off) sh[t] += sh[t + off];
        __syncthreads();
    }
    if (t == 0) {
        double var = sh[0] / (double)B;
        double stdv = sqrt(var) + 1e-8;
        double icir = mean / stdv;
        out[0] = (float)(-icir + 0.1 * stdv);
    }
}

extern "C" void kernel_launch(void* const* d_in, const int* in_sizes, int n_in,
                              void* d_out, int out_size, void* d_ws,
                              size_t ws_size, hipStream_t stream) {
    const float* pred = (const float*)d_in[0];
    const float* tru = (const float*)d_in[1];
    const int B = in_sizes[0] / N_ELEM; // 90

    char* ws = (char*)d_ws;
    unsigned long long* S = (unsigned long long*)ws;
    const size_t off0 = 4096;
    // per chunked row: blockHist 512KB + rec 2MB + rankP (both sides) 2MB
    const size_t perRow = (size_t)NBLK * NBINS * 4 + (size_t)N_ELEM * 8 +
                          (size_t)N_ELEM * 4 * 2;
    int R = (int)((ws_size > off0 ? ws_size - off0 : 0) / perRow);
    if (R > B) R = B;
    if (R < 1) R = 1;

    unsigned* blockHist = (unsigned*)(ws + off0);
    uint2* rec = (uint2*)(ws + off0 + (size_t)R * NBLK * NBINS * 4);
    unsigned* rankP = (unsigned*)(ws + off0 + (size_t)R * NBLK * NBINS * 4 +
                                  (size_t)R * N_ELEM * 8);

    hipMemsetAsync(S, 0, (size_t)B * 8, stream);

    for (int r0 = 0; r0 < B; r0 += R) {
        int RR = (B - r0 < R) ? (B - r0) : R;
        for (int side = 0; side < 2; side++) {
            const float* x = side ? tru : pred;
            hist_kernel<<<dim3(NBLK, RR), 512, 0, stream>>>(x, r0, blockHist);
            scan_kernel<<<RR, 256, 0, stream>>>(blockHist);
            scatter_kernel<<<dim3(NBLK, RR), 512, 0, stream>>>(x, r0, blockHist,
                                                               rec);
            rank_kernel<<<dim3(NBINS / BPB, RR), 256, 0, stream>>>(
                rec, blockHist, rankP, side);
        }
        dot_kernel<<<dim3(N_ELEM / 8192, RR), 256, 0, stream>>>(rankP, S, r0);
    }
    finalize_kernel<<<1, 128, 0, stream>>>(S, B, (float*)d_out);
}

// Round 5
// 1430.838 us; speedup vs baseline: 42.6537x; 1.4520x over previous
//
#include <hip/hip_runtime.h>
#include <stdint.h>

#define N_ELEM 262144
#define NC 512      /* coarse scatter buckets */
#define NFINE 16384 /* fine bins = NC * 32 */
#define TILE 32768
#define NBLK (N_ELEM / TILE) /* 8 */
#define CAP 4096 /* LDS capacity per coarse bucket; center ~3300 expected */

__device__ __forceinline__ unsigned key_of(float x) {
    unsigned u = __float_as_uint(x);
    return u ^ ((u & 0x80000000u) ? 0xFFFFFFFFu : 0x80000000u);
}

// Monotone (non-decreasing) float -> fine bin in [0, 16384). floor((x+8)*1024)
// is monotone; clamping only affects load balance, never correctness (in-bin
// compares use exact keys). coarse = fine>>5, sub = fine&31.
__device__ __forceinline__ int fine_of(float x) {
    int f = (int)floorf((x + 8.0f) * 1024.0f);
    f = f < 0 ? 0 : (f > NFINE - 1 ? NFINE - 1 : f);
    return f;
}

// --- Kernel A: per-(rowside,block) histogram of 512 coarse buckets ---------
__global__ __launch_bounds__(256) void hist_kernel(
    const float* __restrict__ pred, const float* __restrict__ tru, int r0,
    unsigned* __restrict__ bh) {
    __shared__ unsigned h[NC];
    const int rs = blockIdx.y, blk = blockIdx.x;
    const int row = r0 + (rs >> 1);
    const float* x = (rs & 1) ? tru : pred;
    for (int i = threadIdx.x; i < NC; i += 256) h[i] = 0;
    __syncthreads();
    const float4* p =
        (const float4*)(x + (size_t)row * N_ELEM + (size_t)blk * TILE);
    for (int i = threadIdx.x; i < TILE / 4; i += 256) {
        float4 v = p[i];
        atomicAdd(&h[fine_of(v.x) >> 5], 1u);
        atomicAdd(&h[fine_of(v.y) >> 5], 1u);
        atomicAdd(&h[fine_of(v.z) >> 5], 1u);
        atomicAdd(&h[fine_of(v.w) >> 5], 1u);
    }
    __syncthreads();
    unsigned* out = bh + ((size_t)rs * NBLK + blk) * NC;
    for (int i = threadIdx.x; i < NC; i += 256) out[i] = h[i];
}

// --- Kernel B: per-rowside scan -> per-block scatter starts ----------------
// After this, the blk-0 plane holds the rowside-level coarse exclusive prefix.
__global__ __launch_bounds__(512) void scan_kernel(unsigned* __restrict__ bh) {
    __shared__ unsigned ss[NC];
    const int rs = blockIdx.x;
    unsigned* p = bh + (size_t)rs * NBLK * NC;
    const int c = threadIdx.x; // one thread per coarse bucket
    unsigned cnts[NBLK];
    unsigned tot = 0;
    for (int b = 0; b < NBLK; b++) {
        cnts[b] = p[(size_t)b * NC + c];
        tot += cnts[b];
    }
    ss[c] = tot;
    __syncthreads();
    for (int off = 1; off < NC; off <<= 1) {
        unsigned v = (c >= off) ? ss[c - off] : 0u;
        __syncthreads();
        ss[c] += v;
        __syncthreads();
    }
    unsigned pre = ss[c] - tot; // exclusive
    for (int b = 0; b < NBLK; b++) {
        p[(size_t)b * NC + c] = pre;
        pre += cnts[b];
    }
}

// --- Kernel C: scatter (key, sub<<18|idx) grouped by coarse bucket ---------
// Each block owns pre-reserved contiguous ranges per bucket -> consecutive
// write addresses per bucket per block -> full-cacheline accumulation in L2.
__global__ __launch_bounds__(256) void scatter_kernel(
    const float* __restrict__ pred, const float* __restrict__ tru, int r0,
    const unsigned* __restrict__ bh, uint2* __restrict__ rec) {
    __shared__ unsigned cur[NC];
    const int rs = blockIdx.y, blk = blockIdx.x;
    const int row = r0 + (rs >> 1);
    const float* x = (rs & 1) ? tru : pred;
    const unsigned* st = bh + ((size_t)rs * NBLK + blk) * NC;
    for (int i = threadIdx.x; i < NC; i += 256) cur[i] = st[i];
    __syncthreads();
    const float4* p =
        (const float4*)(x + (size_t)row * N_ELEM + (size_t)blk * TILE);
    uint2* rr = rec + (size_t)rs * N_ELEM;
    const int ib = blk * TILE;
    for (int i = threadIdx.x; i < TILE / 4; i += 256) {
        float4 v = p[i];
        int i0 = ib + i * 4;
        float vv[4] = {v.x, v.y, v.z, v.w};
#pragma unroll
        for (int k = 0; k < 4; k++) {
            int f = fine_of(vv[k]);
            unsigned pos = atomicAdd(&cur[f >> 5], 1u);
            rr[pos] = make_uint2(
                key_of(vv[k]),
                ((unsigned)(f & 31) << 18) | (unsigned)(i0 + k));
        }
    }
}

// --- Kernel D: per coarse bucket: LDS counting-sort by 5-bit sub-bin, then
// exact in-sub-bin ordinal rank (broadcast-friendly LDS scans).
// side==0: write rank into rp0[idx]; side==1: gather rp0[idx], acc S[row].
__global__ __launch_bounds__(256) void rank_kernel(
    const uint2* __restrict__ rec, const unsigned* __restrict__ bh,
    unsigned* __restrict__ rp0, unsigned long long* __restrict__ S, int r0,
    int side) {
    const int c = blockIdx.x, crow = blockIdx.y;
    const int rs = crow * 2 + side;
    const unsigned* pf = bh + (size_t)rs * NBLK * NC; // blk0 = rowside prefix
    const unsigned base = pf[c];
    const unsigned end = (c + 1 < NC) ? pf[c + 1] : (unsigned)N_ELEM;
    const int n = (int)(end - base);
    const int t = threadIdx.x;
    const uint2* r = rec + (size_t)rs * N_ELEM + base;
    unsigned* rp = rp0 + (size_t)crow * N_ELEM;
    unsigned long long acc = 0;
    __shared__ unsigned long long red[4];

    if (n > 0 && n <= CAP) {
        __shared__ unsigned skS[CAP], syS[CAP];
        __shared__ unsigned cnt[32], bas[33], curq[32];
        if (t < 32) cnt[t] = 0;
        __syncthreads();
        for (int p = t; p < n; p += 256)
            atomicAdd(&cnt[(r[p].y >> 18) & 31], 1u);
        __syncthreads();
        if (t == 0) {
            unsigned s = 0;
            for (int i = 0; i < 32; i++) {
                bas[i] = s;
                s += cnt[i];
            }
            bas[32] = s;
        }
        __syncthreads();
        if (t < 32) curq[t] = bas[t];
        __syncthreads();
        for (int p = t; p < n; p += 256) {
            uint2 e = r[p];
            unsigned pos = atomicAdd(&curq[(e.y >> 18) & 31], 1u);
            skS[pos] = e.x;
            syS[pos] = e.y;
        }
        __syncthreads();
        for (int p = t; p < n; p += 256) {
            unsigned y = syS[p];
            unsigned sub = (y >> 18) & 31;
            unsigned lo = bas[sub], hi = bas[sub + 1];
            unsigned long long myK =
                ((unsigned long long)skS[p] << 32) | (unsigned)p;
            unsigned cb = 0;
            for (unsigned k = lo; k < hi; k++) {
                unsigned long long K =
                    ((unsigned long long)skS[k] << 32) | k;
                cb += (K < myK) ? 1u : 0u;
            }
            unsigned rank = base + lo + cb + 1u;
            unsigned idx = y & 0x3FFFFu;
            if (!side)
                rp[idx] = rank;
            else
                acc += (unsigned long long)rp[idx] * (unsigned long long)rank;
        }
    } else if (n > CAP) { // safety fallback (not expected for N(0,1) inputs)
        for (int p = t; p < n; p += 256) {
            uint2 e = r[p];
            unsigned sub = (e.y >> 18) & 31;
            unsigned cb = 0;
            for (int k = 0; k < n; k++) {
                uint2 ek = r[k];
                unsigned s2 = (ek.y >> 18) & 31;
                bool less =
                    (s2 < sub) ||
                    (s2 == sub &&
                     (ek.x < e.x || (ek.x == e.x && k < p)));
                cb += less ? 1u : 0u;
            }
            unsigned rank = base + cb + 1u;
            unsigned idx = e.y & 0x3FFFFu;
            if (!side)
                rp[idx] = rank;
            else
                acc += (unsigned long long)rp[idx] * (unsigned long long)rank;
        }
    }
    if (side) {
        for (int off = 32; off > 0; off >>= 1)
            acc += __shfl_down(acc, off, 64);
        if ((t & 63) == 0) red[t >> 6] = acc;
        __syncthreads();
        if (t == 0) {
            unsigned long long s = red[0] + red[1] + red[2] + red[3];
            if (s) atomicAdd(&S[r0 + crow], s);
        }
    }
}

// --- Kernel E: closed-form Pearson of two exact permutations + loss --------
__global__ void finalize_kernel(const unsigned long long* __restrict__ S, int B,
                                float* __restrict__ out) {
    __shared__ double sh[128];
    const int t = threadIdx.x;
    const double Nd = (double)N_ELEM;
    const double m = (Nd + 1.0) * 0.5;
    const double q = Nd * (Nd * Nd - 1.0) / 12.0;
    double c = 0.0;
    if (t < B) {
        double num = (double)(long long)S[t] - Nd * m * m;
        c = num / sqrt(q * q + 1e-8);
    }
    sh[t] = c;
    __syncthreads();
    for (int off = 64; off > 0; off >>= 1) {
        if (t < off) sh[t] += sh[t + off];
        __syncthreads();
    }
    double mean = sh[0] / (double)B;
    __syncthreads();
    double d = (t < B) ? (c - mean) : 0.0;
    sh[t] = d * d;
    __syncthreads();
    for (int off = 64; off > 0; off >>= 1) {
        if (t < off) sh[t] += sh[t + off];
        __syncthreads();
    }
    if (t == 0) {
        double var = sh[0] / (double)B;
        double stdv = sqrt(var) + 1e-8;
        double icir = mean / stdv;
        out[0] = (float)(-icir + 0.1 * stdv);
    }
}

extern "C" void kernel_launch(void* const* d_in, const int* in_sizes, int n_in,
                              void* d_out, int out_size, void* d_ws,
                              size_t ws_size, hipStream_t stream) {
    const float* pred = (const float*)d_in[0];
    const float* tru = (const float*)d_in[1];
    const int B = in_sizes[0] / N_ELEM; // 90

    char* ws = (char*)d_ws;
    unsigned long long* S = (unsigned long long*)ws;
    const size_t off0 = 4096;
    // per chunked row: bh 2*8*512*4 = 32KB, rec both sides 4MB, rp0 1MB
    const size_t bhRow = (size_t)2 * NBLK * NC * 4;
    const size_t recRow = (size_t)2 * N_ELEM * 8;
    const size_t rpRow = (size_t)N_ELEM * 4;
    const size_t perRow = bhRow + recRow + rpRow;
    int R = (int)((ws_size > off0 ? ws_size - off0 : 0) / perRow);
    if (R > B) R = B;
    if (R < 1) R = 1;

    unsigned* bh = (unsigned*)(ws + off0);
    uint2* rec = (uint2*)(ws + off0 + (size_t)R * bhRow);
    unsigned* rp0 = (unsigned*)(ws + off0 + (size_t)R * bhRow + (size_t)R * recRow);

    hipMemsetAsync(S, 0, (size_t)B * 8, stream);

    for (int r0 = 0; r0 < B; r0 += R) {
        int RR = (B - r0 < R) ? (B - r0) : R;
        hist_kernel<<<dim3(NBLK, 2 * RR), 256, 0, stream>>>(pred, tru, r0, bh);
        scan_kernel<<<2 * RR, NC, 0, stream>>>(bh);
        scatter_kernel<<<dim3(NBLK, 2 * RR), 256, 0, stream>>>(pred, tru, r0,
                                                               bh, rec);
        rank_kernel<<<dim3(NC, RR), 256, 0, stream>>>(rec, bh, rp0, S, r0, 0);
        rank_kernel<<<dim3(NC, RR), 256, 0, stream>>>(rec, bh, rp0, S, r0, 1);
    }
    finalize_kernel<<<1, 128, 0, stream>>>(S, B, (float*)d_out);
}